// Round 8
// baseline (318.600 us; speedup 1.0000x reference)
//
#include <hip/hip_runtime.h>
#include <hip/hip_bf16.h>
#include <math.h>

// PostEncode R8: block-cooperative layer-synchronous MFMA chain.
// R3-R7 post-mortem: the per-wave serial-chain structure always produced
// ~80-100MB phantom WRITE (scratch) + 4x-redundant weight LDS reads. R8
// abandons it: one block (4 waves) per node; each layer is a block-level
// GEMM (wave w owns out-cols [16w,16w+16) for ALL rows); intermediates
// ping-pong via XOR-swizzled LDS ((row&7)<<4); softmax is one plain pass.
// Liveness ~55 VGPR -> spill-proof; waves_per_eu(2,2); 2 blocks/CU @75KB LDS.
// MFMA layout = R2-verified (A: lane(g,c) j -> W[k(s,g,j)][16w+c];
// B: X[k][rowbase+c]; D: lane(g,c) reg r = Y[16w+4g+r][rowbase+c]),
// k(s,g,j)=32s+8g+j for all layers (LDS round-trip each layer).

#define NN 16384
#define LL 50
#define EE 64
#define NUE 6400000  // u2e bf16 elements; r2e table follows

typedef __attribute__((ext_vector_type(8))) short short8;
typedef __attribute__((ext_vector_type(4))) float f32x4;

static __device__ __forceinline__ unsigned short f2bf(float x) {
  __hip_bfloat16 h = __float2bfloat16(x);
  unsigned short u;
  __builtin_memcpy(&u, &h, 2);
  return u;
}

static __device__ __forceinline__ float bf2f(unsigned short u) {
  unsigned int v = ((unsigned int)u) << 16;
  float f;
  __builtin_memcpy(&f, &v, 4);
  return f;
}

static __device__ __forceinline__ f32x4 ld4(const float* p) {
  return *(const f32x4*)p;
}

static __device__ __forceinline__ f32x4 relu4(f32x4 a) {
  f32x4 r;
  r[0] = fmaxf(a[0], 0.f); r[1] = fmaxf(a[1], 0.f);
  r[2] = fmaxf(a[2], 0.f); r[3] = fmaxf(a[3], 0.f);
  return r;
}

#define MFMA(A, B, C) __builtin_amdgcn_mfma_f32_16x16x32_bf16((A), (B), (C), 0, 0, 0)
#define SWZ(row, byteoff) ((byteoff) ^ (((row) & 7) << 4))

// ---------------- conv: u2e,r2e f32 -> bf16 tables ----------------
__global__ __launch_bounds__(256)
void conv_kernel(const float* __restrict__ u2e, const float* __restrict__ r2e,
                 unsigned short* __restrict__ ur_bf) {
  const int total8 = (NUE + 384) / 8;
  for (int i = blockIdx.x * 256 + (int)threadIdx.x; i < total8;
       i += gridDim.x * 256) {
    const long long e0 = (long long)i * 8;
    const float* src = (e0 < NUE) ? (u2e + e0) : (r2e + (e0 - NUE));
    float4 a = *(const float4*)src;
    float4 b = *(const float4*)(src + 4);
    short8 v;
    v[0] = (short)f2bf(a.x); v[1] = (short)f2bf(a.y);
    v[2] = (short)f2bf(a.z); v[3] = (short)f2bf(a.w);
    v[4] = (short)f2bf(b.x); v[5] = (short)f2bf(b.y);
    v[6] = (short)f2bf(b.z); v[7] = (short)f2bf(b.w);
    *reinterpret_cast<short8*>(ur_bf + e0) = v;
  }
}

// ---------------- pack: weights -> frag-ordered bf16 ----------------
// frag idx: L1 [0,1024): (w*4+s)*64+lane ; L2 1024+: (w*2+s)*64+lane ;
// L3 1536+ (A1 rows 0..63) ; L4 2048+. Element j of lane (g=lane>>4,c=lane&15):
// value = W[(32s+8g+j)*64 + 16w + c]   (same enum for ALL layers).
__global__ __launch_bounds__(256)
void pack_kernel(const float* __restrict__ W1_w, const float* __restrict__ W2_w,
                 const float* __restrict__ A1_w, const float* __restrict__ A2_w,
                 unsigned short* __restrict__ frag_ws) {
  int tid = blockIdx.x * blockDim.x + threadIdx.x;
  for (int idx = tid; idx < 2560; idx += gridDim.x * blockDim.x) {
    const float* W;
    int w, s, lane;
    if (idx < 1024) {
      w = idx >> 8; s = (idx >> 6) & 3; lane = idx & 63; W = W1_w;
    } else {
      int r = idx - 1024;
      int li = r >> 9;
      w = (r >> 7) & 3; s = (r >> 6) & 1; lane = r & 63;
      W = (li == 0) ? W2_w : (li == 1) ? A1_w : A2_w;
    }
    const int g = lane >> 4, c = lane & 15;
#pragma unroll
    for (int j = 0; j < 8; ++j)
      frag_ws[idx * 8 + j] = f2bf(W[(32 * s + 8 * g + j) * EE + 16 * w + c]);
  }
}

// ---------------- setup: post + abase (f32) ----------------
__global__ __launch_bounds__(64)
void setup_kernel(const float* __restrict__ content_emb,
                  const int* __restrict__ pr_content,
                  const float* __restrict__ We_w, const float* __restrict__ We_b,
                  const float* __restrict__ A1_w, const float* __restrict__ A1_b,
                  float* __restrict__ post_ws, float* __restrict__ abase_ws) {
  const int n = blockIdx.x;
  const int e = threadIdx.x;
  __shared__ float ce_s[128];
  __shared__ float post_s[64];
  const float* ce = content_emb + (size_t)pr_content[n] * 128;
  ce_s[e] = ce[e];
  ce_s[64 + e] = ce[64 + e];
  __syncthreads();
  float acc = We_b[e];
#pragma unroll 8
  for (int k = 0; k < 128; ++k) acc = fmaf(ce_s[k], We_w[k * EE + e], acc);
  float po = fmaxf(acc, 0.f);
  post_s[e] = po;
  post_ws[n * EE + e] = po;
  __syncthreads();
  float ab = A1_b[e];
#pragma unroll 8
  for (int k = 0; k < 64; ++k) ab = fmaf(post_s[k], A1_w[(64 + k) * EE + e], ab);
  abase_ws[n * EE + e] = ab;
}

// ---------------- fused: block-per-node layer-sync chain ----------------
__global__
__attribute__((amdgpu_flat_work_group_size(256, 256)))
__attribute__((amdgpu_waves_per_eu(2, 2)))
void fused_kernel(const unsigned short* __restrict__ ur_bf,
                  const float* __restrict__ W1_b, const float* __restrict__ W2_b,
                  const float* __restrict__ A2_b,
                  const float* __restrict__ A3_w, const float* __restrict__ A3_b,
                  const float* __restrict__ Ow_w, const float* __restrict__ Ow_b,
                  const int* __restrict__ pu_history,
                  const int* __restrict__ pr_history,
                  const int* __restrict__ lengths,
                  const short8* __restrict__ pf,
                  const float* __restrict__ post_ws,
                  const float* __restrict__ abase_ws,
                  float* __restrict__ out) {
  const int tid = (int)threadIdx.x;
  const int lane = tid & 63;
  const int w = tid >> 6;           // wave id = out-col tile
  const int g = lane >> 4;
  const int c = lane & 15;

  __shared__ short8 wf_s[2560];                 // 40 KB weight frags
  __shared__ float bias_s[256];                 // b1|b2|A2_b|A3_w
  __shared__ __align__(16) unsigned char xb0[16384];  // X0 (K=128) / X3
  __shared__ __align__(16) unsigned char xb1[8192];   // X1
  __shared__ __align__(16) unsigned char xb2[8192];   // X2 = o (bf16)
  __shared__ float lpart[4][64];
  __shared__ float att_s[64];
  __shared__ float hp_s[4][64];

  for (int i = tid; i < 2560; i += 256) wf_s[i] = pf[i];
  if (tid < 64) {
    bias_s[tid]       = W1_b[tid];
    bias_s[64 + tid]  = W2_b[tid];
    bias_s[128 + tid] = A2_b[tid];
    bias_s[192 + tid] = A3_w[tid];
  }
  __syncthreads();

  const float b3 = A3_b[0];
  const unsigned short* rbase = ur_bf + NUE;

  for (int n = blockIdx.x; n < NN; n += gridDim.x) {
    const int len = lengths[n];            // block-uniform
    const int ntile = (len + 15) >> 4;     // 1..4
    const int base = n * LL;

    // ---- stage X0: rows 0..ntile*16-1, 256B/row = [u(128B);r(128B)] ----
#pragma unroll
    for (int i = 0; i < 4; ++i) {
      if (i < ntile) {
        const int l = i * 16 + (tid >> 4);
        const int ch = tid & 15;
        short8 v = {0, 0, 0, 0, 0, 0, 0, 0};
        if (l < len) {
          if (ch < 8) {
            const int pu = pu_history[base + l];
            v = *(const short8*)(ur_bf + (size_t)pu * EE + ch * 8);
          } else {
            const int pr = pr_history[base + l];
            v = *(const short8*)(rbase + (size_t)pr * EE + (ch - 8) * 8);
          }
        }
        *(short8*)(xb0 + SWZ(l, l * 256 + ch * 16)) = v;
      }
    }
    __syncthreads();

    f32x4 acc[4];

    // ---- L1: X1 = relu(X0 @ W1 + b1), K=128 ----
    {
      const f32x4 binit = ld4(bias_s + 16 * w + 4 * g);
#pragma unroll
      for (int rt = 0; rt < 4; ++rt) acc[rt] = binit;
#pragma unroll
      for (int s = 0; s < 4; ++s) {
        const short8 af = wf_s[(w * 4 + s) * 64 + lane];
#pragma unroll
        for (int rt = 0; rt < 4; ++rt)
          if (rt < ntile) {
            const int row = rt * 16 + c;
            const short8 bf =
                *(const short8*)(xb0 + SWZ(row, row * 256 + s * 64 + g * 16));
            acc[rt] = MFMA(af, bf, acc[rt]);
          }
      }
#pragma unroll
      for (int rt = 0; rt < 4; ++rt)
        if (rt < ntile) {
          const f32x4 v = relu4(acc[rt]);
          ushort4 p;
          p.x = f2bf(v[0]); p.y = f2bf(v[1]); p.z = f2bf(v[2]); p.w = f2bf(v[3]);
          const int row = rt * 16 + c;
          *(ushort4*)(xb1 + SWZ(row, row * 128 + w * 32 + g * 8)) = p;
        }
    }
    __syncthreads();

    // ---- L2: o = relu(X1 @ W2 + b2), K=64 ----
    {
      const f32x4 binit = ld4(bias_s + 64 + 16 * w + 4 * g);
#pragma unroll
      for (int rt = 0; rt < 4; ++rt) acc[rt] = binit;
#pragma unroll
      for (int s = 0; s < 2; ++s) {
        const short8 af = wf_s[1024 + (w * 2 + s) * 64 + lane];
#pragma unroll
        for (int rt = 0; rt < 4; ++rt)
          if (rt < ntile) {
            const int row = rt * 16 + c;
            const short8 bf =
                *(const short8*)(xb1 + SWZ(row, row * 128 + s * 64 + g * 16));
            acc[rt] = MFMA(af, bf, acc[rt]);
          }
      }
#pragma unroll
      for (int rt = 0; rt < 4; ++rt)
        if (rt < ntile) {
          const f32x4 v = relu4(acc[rt]);
          ushort4 p;
          p.x = f2bf(v[0]); p.y = f2bf(v[1]); p.z = f2bf(v[2]); p.w = f2bf(v[3]);
          const int row = rt * 16 + c;
          *(ushort4*)(xb2 + SWZ(row, row * 128 + w * 32 + g * 8)) = p;
        }
    }
    __syncthreads();

    // ---- L3: a1 = relu(o @ A1[0:64] + abase[n]), K=64 -> X3 (=xb0) ----
    {
      const f32x4 binit = ld4(abase_ws + (size_t)n * EE + 16 * w + 4 * g);
#pragma unroll
      for (int rt = 0; rt < 4; ++rt) acc[rt] = binit;
#pragma unroll
      for (int s = 0; s < 2; ++s) {
        const short8 af = wf_s[1536 + (w * 2 + s) * 64 + lane];
#pragma unroll
        for (int rt = 0; rt < 4; ++rt)
          if (rt < ntile) {
            const int row = rt * 16 + c;
            const short8 bf =
                *(const short8*)(xb2 + SWZ(row, row * 128 + s * 64 + g * 16));
            acc[rt] = MFMA(af, bf, acc[rt]);
          }
      }
#pragma unroll
      for (int rt = 0; rt < 4; ++rt)
        if (rt < ntile) {
          const f32x4 v = relu4(acc[rt]);
          ushort4 p;
          p.x = f2bf(v[0]); p.y = f2bf(v[1]); p.z = f2bf(v[2]); p.w = f2bf(v[3]);
          const int row = rt * 16 + c;
          *(ushort4*)(xb0 + SWZ(row, row * 128 + w * 32 + g * 8)) = p;
        }
    }
    __syncthreads();

    // ---- L4: a2 = relu(X3 @ A2 + b); logit partials ----
    {
      const f32x4 binit = ld4(bias_s + 128 + 16 * w + 4 * g);
#pragma unroll
      for (int rt = 0; rt < 4; ++rt) acc[rt] = binit;
#pragma unroll
      for (int s = 0; s < 2; ++s) {
        const short8 af = wf_s[2048 + (w * 2 + s) * 64 + lane];
#pragma unroll
        for (int rt = 0; rt < 4; ++rt)
          if (rt < ntile) {
            const int row = rt * 16 + c;
            const short8 bf =
                *(const short8*)(xb0 + SWZ(row, row * 128 + s * 64 + g * 16));
            acc[rt] = MFMA(af, bf, acc[rt]);
          }
      }
      const f32x4 a3 = ld4(bias_s + 192 + 16 * w + 4 * g);
#pragma unroll
      for (int rt = 0; rt < 4; ++rt)
        if (rt < ntile) {
          const f32x4 r = relu4(acc[rt]);
          float p = r[0] * a3[0];
          p = fmaf(r[1], a3[1], p);
          p = fmaf(r[2], a3[2], p);
          p = fmaf(r[3], a3[3], p);
          p += __shfl_xor(p, 16);
          p += __shfl_xor(p, 32);          // sum over g
          if (lane < 16) lpart[w][rt * 16 + lane] = p;
        }
    }
    __syncthreads();

    // ---- softmax over rows (wave 0) ----
    if (tid < 64) {
      float lg = -INFINITY;
      if (tid < len)
        lg = lpart[0][tid] + lpart[1][tid] + lpart[2][tid] + lpart[3][tid] + b3;
      float m = lg;
#pragma unroll
      for (int off = 32; off > 0; off >>= 1) m = fmaxf(m, __shfl_xor(m, off));
      const float e = __expf(lg - m);
      float sm = e;
#pragma unroll
      for (int off = 32; off > 0; off >>= 1) sm += __shfl_xor(sm, off);
      att_s[tid] = e / sm;
    }
    __syncthreads();

    // ---- hist partials: hp[q][col] = sum_{rows of q} att*o ----
    {
      const int col = tid & 63;
      const int q = tid >> 6;
      float hp = 0.f;
      if (q < ntile) {
#pragma unroll 4
        for (int i = 0; i < 16; ++i) {
          const int row = q * 16 + i;
          const unsigned short ov =
              *(const unsigned short*)(xb2 + SWZ(row, row * 128 + col * 2));
          hp = fmaf(att_s[row], bf2f(ov), hp);
        }
      }
      hp_s[q][col] = hp;
    }
    __syncthreads();

    // ---- epilogue (wave 0): out = relu([hist;post] @ Ow + b) ----
    if (tid < 64) {
      const float hv =
          hp_s[0][tid] + hp_s[1][tid] + hp_s[2][tid] + hp_s[3][tid];
      const float po = post_ws[(size_t)n * EE + tid];
      float acc2 = Ow_b[tid];
#pragma unroll 8
      for (int k = 0; k < 64; ++k)
        acc2 = fmaf(__shfl(hv, k), Ow_w[k * EE + tid], acc2);
#pragma unroll 8
      for (int k = 0; k < 64; ++k)
        acc2 = fmaf(__shfl(po, k), Ow_w[(64 + k) * EE + tid], acc2);
      out[(size_t)n * EE + tid] = fmaxf(acc2, 0.f);
    }
    __syncthreads();  // protect LDS before next node
  }
}

// ---------------- R1 fallback (all-f32, no workspace) ----------------
template <int K>
__device__ __forceinline__ void mm2(const float* row0, const float* row1,
                                    const float* __restrict__ W, int e,
                                    float& acc0, float& acc1) {
  const float4* r0 = (const float4*)row0;
  const float4* r1 = (const float4*)row1;
#pragma unroll 4
  for (int k4 = 0; k4 < K / 4; ++k4) {
    float4 va = r0[k4];
    float4 vb = r1[k4];
    const float* w = W + (k4 * 4) * EE + e;
    float w0 = w[0], w1 = w[EE], w2 = w[2 * EE], w3 = w[3 * EE];
    acc0 = fmaf(va.x, w0, acc0);  acc1 = fmaf(vb.x, w0, acc1);
    acc0 = fmaf(va.y, w1, acc0);  acc1 = fmaf(vb.y, w1, acc1);
    acc0 = fmaf(va.z, w2, acc0);  acc1 = fmaf(vb.z, w2, acc1);
    acc0 = fmaf(va.w, w3, acc0);  acc1 = fmaf(vb.w, w3, acc1);
  }
}

__global__ __launch_bounds__(256, 4)
void postenc_kernel(
    const float* __restrict__ u2e, const float* __restrict__ r2e,
    const float* __restrict__ content_emb,
    const float* __restrict__ We_w, const float* __restrict__ We_b,
    const float* __restrict__ W1_w, const float* __restrict__ W1_b,
    const float* __restrict__ W2_w, const float* __restrict__ W2_b,
    const float* __restrict__ A1_w, const float* __restrict__ A1_b,
    const float* __restrict__ A2_w, const float* __restrict__ A2_b,
    const float* __restrict__ A3_w, const float* __restrict__ A3_b,
    const float* __restrict__ Ow_w, const float* __restrict__ Ow_b,
    const int* __restrict__ pu_history, const int* __restrict__ pr_history,
    const int* __restrict__ lengths, const int* __restrict__ pr_content,
    float* __restrict__ out) {
  const int n = blockIdx.x;
  const int tid = (int)threadIdx.x;
  const int e = tid & 63;
  const int g = tid >> 6;

  __shared__ float post_s[EE];
  __shared__ float abase_s[EE];
  __shared__ float in_s[8][128];
  __shared__ float x_s[8][EE];
  __shared__ float a_s[8][EE];
  __shared__ float o_s[56][EE];
  __shared__ float logit_s[EE];
  __shared__ float att_s[EE];
  __shared__ float red_s[4][EE];

  const int len = lengths[n];
  float p = 0.f;

  if (g == 0) {
    const float* ce = content_emb + (size_t)pr_content[n] * 128;
    float acc = We_b[e];
#pragma unroll 4
    for (int k = 0; k < 128; ++k) acc = fmaf(ce[k], We_w[k * EE + e], acc);
    p = fmaxf(acc, 0.f);
    post_s[e] = p;
    float ab = A1_b[e];
#pragma unroll
    for (int k = 0; k < 64; ++k) {
      float pk = __shfl(p, k);
      ab = fmaf(pk, A1_w[(64 + k) * EE + e], ab);
    }
    abase_s[e] = ab;
    logit_s[e] = -INFINITY;
  }
  __syncthreads();

  for (int lb = 0; lb < 56; lb += 8) {
    const int l0 = lb + g;
    const int l1 = l0 + 4;
    const bool v0 = l0 < LL;
    const bool v1 = l1 < LL;

    int pu0 = 0, pr0 = 0, pu1 = 0, pr1 = 0;
    if (v0) { pu0 = pu_history[n * LL + l0]; pr0 = pr_history[n * LL + l0]; }
    if (v1) { pu1 = pu_history[n * LL + l1]; pr1 = pr_history[n * LL + l1]; }
    in_s[g][e]          = v0 ? u2e[(size_t)pu0 * EE + e] : 0.f;
    in_s[g][64 + e]     = v0 ? r2e[pr0 * EE + e]         : 0.f;
    in_s[g + 4][e]      = v1 ? u2e[(size_t)pu1 * EE + e] : 0.f;
    in_s[g + 4][64 + e] = v1 ? r2e[pr1 * EE + e]         : 0.f;
    __syncthreads();

    float acc0 = W1_b[e], acc1 = acc0;
    mm2<128>(in_s[g], in_s[g + 4], W1_w, e, acc0, acc1);
    x_s[g][e]     = fmaxf(acc0, 0.f);
    x_s[g + 4][e] = fmaxf(acc1, 0.f);
    __syncthreads();

    acc0 = W2_b[e]; acc1 = acc0;
    mm2<64>(x_s[g], x_s[g + 4], W2_w, e, acc0, acc1);
    float o0 = fmaxf(acc0, 0.f);
    float o1 = fmaxf(acc1, 0.f);
    if (v0) o_s[l0][e] = o0;
    if (v1) o_s[l1][e] = o1;
    x_s[g][e]     = o0;
    x_s[g + 4][e] = o1;
    __syncthreads();

    acc0 = abase_s[e]; acc1 = acc0;
    mm2<64>(x_s[g], x_s[g + 4], A1_w, e, acc0, acc1);
    a_s[g][e]     = fmaxf(acc0, 0.f);
    a_s[g + 4][e] = fmaxf(acc1, 0.f);
    __syncthreads();

    acc0 = A2_b[e]; acc1 = acc0;
    mm2<64>(a_s[g], a_s[g + 4], A2_w, e, acc0, acc1);
    float w3 = A3_w[e];
    float p0 = fmaxf(acc0, 0.f) * w3;
    float p1 = fmaxf(acc1, 0.f) * w3;
#pragma unroll
    for (int off = 32; off > 0; off >>= 1) {
      p0 += __shfl_xor(p0, off);
      p1 += __shfl_xor(p1, off);
    }
    if (e == 0) {
      float b3 = A3_b[0];
      if (l0 < len) logit_s[l0] = p0 + b3;
      if (l1 < len) logit_s[l1] = p1 + b3;
    }
    __syncthreads();
  }

  if (g == 0) {
    float lg = logit_s[e];
    float m = lg;
#pragma unroll
    for (int off = 32; off > 0; off >>= 1) m = fmaxf(m, __shfl_xor(m, off));
    float pe = __expf(lg - m);
    float sm = pe;
#pragma unroll
    for (int off = 32; off > 0; off >>= 1) sm += __shfl_xor(sm, off);
    att_s[e] = pe / sm;
  }
  __syncthreads();

  {
    const int l_lo = 13 * g;
    const int l_hi = (13 * g + 13 < LL) ? 13 * g + 13 : LL;
    float h = 0.f;
    for (int l = l_lo; l < l_hi; ++l) h = fmaf(att_s[l], o_s[l][e], h);
    red_s[g][e] = h;
  }
  __syncthreads();

  if (g == 0) {
    float h = red_s[0][e] + red_s[1][e] + red_s[2][e] + red_s[3][e];
    float acc = Ow_b[e];
#pragma unroll
    for (int k = 0; k < 64; ++k) {
      float hk = __shfl(h, k);
      acc = fmaf(hk, Ow_w[k * EE + e], acc);
    }
#pragma unroll
    for (int k = 0; k < 64; ++k) {
      float pk = __shfl(p, k);
      acc = fmaf(pk, Ow_w[(64 + k) * EE + e], acc);
    }
    out[(size_t)n * EE + e] = fmaxf(acc, 0.f);
  }
}

// ---------------- launcher ----------------
extern "C" void kernel_launch(void* const* d_in, const int* in_sizes, int n_in,
                              void* d_out, int out_size, void* d_ws, size_t ws_size,
                              hipStream_t stream) {
  const float* u2e         = (const float*)d_in[0];
  const float* r2e         = (const float*)d_in[1];
  const float* content_emb = (const float*)d_in[2];
  const float* We_w = (const float*)d_in[3];
  const float* We_b = (const float*)d_in[4];
  const float* W1_w = (const float*)d_in[5];
  const float* W1_b = (const float*)d_in[6];
  const float* W2_w = (const float*)d_in[7];
  const float* W2_b = (const float*)d_in[8];
  const float* A1_w = (const float*)d_in[9];
  const float* A1_b = (const float*)d_in[10];
  const float* A2_w = (const float*)d_in[11];
  const float* A2_b = (const float*)d_in[12];
  const float* A3_w = (const float*)d_in[13];
  const float* A3_b = (const float*)d_in[14];
  const float* Ow_w = (const float*)d_in[15];
  const float* Ow_b = (const float*)d_in[16];
  // d_in[17] = nodes (unused)
  const int* pu_history = (const int*)d_in[18];
  const int* pr_history = (const int*)d_in[19];
  const int* lengths    = (const int*)d_in[20];
  const int* pr_content = (const int*)d_in[21];
  float* out = (float*)d_out;

  // workspace layout (bytes)
  const size_t FR_OFF  = 0;                        // 2560 short8 = 40960 B
  const size_t PO_OFF  = 65536;                    // post f32 [N*64]
  const size_t AB_OFF  = PO_OFF + (size_t)NN * EE * 4;
  const size_t UBF_OFF = AB_OFF + (size_t)NN * EE * 4;   // bf16 u2e+r2e
  const size_t NEED    = UBF_OFF + (size_t)(NUE + 384) * 2;  // ~21.3 MB

  if (ws_size < NEED) {
    postenc_kernel<<<NN, 256, 0, stream>>>(
        u2e, r2e, content_emb, We_w, We_b, W1_w, W1_b, W2_w, W2_b,
        A1_w, A1_b, A2_w, A2_b, A3_w, A3_b, Ow_w, Ow_b,
        pu_history, pr_history, lengths, pr_content, out);
    return;
  }

  char* wsp = (char*)d_ws;
  unsigned short* frag_ws = (unsigned short*)(wsp + FR_OFF);
  float* post_ws  = (float*)(wsp + PO_OFF);
  float* abase_ws = (float*)(wsp + AB_OFF);
  unsigned short* ur_bf = (unsigned short*)(wsp + UBF_OFF);

  conv_kernel<<<2048, 256, 0, stream>>>(u2e, r2e, ur_bf);
  pack_kernel<<<4, 256, 0, stream>>>(W1_w, W2_w, A1_w, A2_w, frag_ws);
  setup_kernel<<<NN, 64, 0, stream>>>(content_emb, pr_content, We_w, We_b,
                                      A1_w, A1_b, post_ws, abase_ws);
  fused_kernel<<<512, 256, 0, stream>>>(
      ur_bf, W1_b, W2_b, A2_b, A3_w, A3_b, Ow_w, Ow_b,
      pu_history, pr_history, lengths, (const short8*)frag_ws,
      post_ws, abase_ws, out);
}